// Round 9
// baseline (82.689 us; speedup 1.0000x reference)
//
#include <hip/hip_runtime.h>

#define NN 512
#define FMAGIC 0x5AD0F1A6u
#define TMAGIC 0x3C96E5B1u

// ---------------- single kernel: tiled GEMM -> 16-block group wait -> rows ----
// 256 blocks x 256 threads. Block b: (1) computes S-tile (b>>4, b&15) with the
// round-0 bitwise-proven 32x32 LDS GEMM (128 KB/block global traffic -- 8x less
// per-CU than the per-anchor full-P dot, which r4/r5/r6/r8 showed is per-CU
// L1-fill-bound at ~1 MB/CU); (2) publishes the tile as RELAXED agent-scope
// atomic bit-stores (coherence-point transport, no L2 flush storm -- r3
// lesson); (3) waits only on its OWN group's 16 tile flags (16-block
// sub-barrier, all blocks resident at 1/CU -> deadlock-free); (4) runs the
// verbatim rows phase on atomic-loaded S rows; (5) r4-proven atomic tail.
__global__ __launch_bounds__(256) void sap_one(const float* __restrict__ P,
                                               const int* __restrict__ labels,
                                               unsigned* __restrict__ S_bits,
                                               unsigned* __restrict__ tflags,
                                               unsigned* __restrict__ pa_bits,
                                               unsigned* __restrict__ pflags,
                                               float* __restrict__ out) {
    __shared__ float As[32][33];
    __shared__ float Bs[32][33];
    __shared__ float srow[NN];
    __shared__ float posf[NN];
    __shared__ int   poslist[NN];
    __shared__ int   npos_cnt;
    __shared__ float wave_part[4];
    __shared__ float pa_out[2];
    __shared__ float sh[256];

    const int t = threadIdx.x;
    const int b = blockIdx.x;

    // ================= Phase 1: S-tile (verbatim round-0 gemm) ===============
    {
        const int tx = t & 15, ty = t >> 4;
        const int i0 = (b >> 4) * 32, j0 = (b & 15) * 32;
        float acc00 = 0.f, acc01 = 0.f, acc10 = 0.f, acc11 = 0.f;
        const int lr = t >> 3;        // 0..31
        const int lc = (t & 7) * 4;   // 0,4,...,28

        for (int kt = 0; kt < NN; kt += 32) {
            float4 a  = *(const float4*)&P[(i0 + lr) * NN + kt + lc];
            float4 bb = *(const float4*)&P[(j0 + lr) * NN + kt + lc];
            As[lr][lc + 0] = a.x;  As[lr][lc + 1] = a.y;
            As[lr][lc + 2] = a.z;  As[lr][lc + 3] = a.w;
            Bs[lr][lc + 0] = bb.x; Bs[lr][lc + 1] = bb.y;
            Bs[lr][lc + 2] = bb.z; Bs[lr][lc + 3] = bb.w;
            __syncthreads();
#pragma unroll
            for (int kk = 0; kk < 32; kk++) {
                float a0 = As[2 * ty][kk], a1 = As[2 * ty + 1][kk];
                float b0 = Bs[2 * tx][kk], b1 = Bs[2 * tx + 1][kk];
                acc00 += a0 * b0; acc01 += a0 * b1;
                acc10 += a1 * b0; acc11 += a1 * b1;
            }
            __syncthreads();
        }
        // publish tile through the coherence point (relaxed atomics keep bits)
        const int i = i0 + 2 * ty, j = j0 + 2 * tx;
        __hip_atomic_store(&S_bits[i * NN + j],           __float_as_uint(acc00),
                           __ATOMIC_RELAXED, __HIP_MEMORY_SCOPE_AGENT);
        __hip_atomic_store(&S_bits[i * NN + j + 1],       __float_as_uint(acc01),
                           __ATOMIC_RELAXED, __HIP_MEMORY_SCOPE_AGENT);
        __hip_atomic_store(&S_bits[(i + 1) * NN + j],     __float_as_uint(acc10),
                           __ATOMIC_RELAXED, __HIP_MEMORY_SCOPE_AGENT);
        __hip_atomic_store(&S_bits[(i + 1) * NN + j + 1], __float_as_uint(acc11),
                           __ATOMIC_RELAXED, __HIP_MEMORY_SCOPE_AGENT);
        asm volatile("s_waitcnt vmcnt(0)" ::: "memory");   // drain before flag
        __syncthreads();                                   // all 1024 stores done
        if (t == 0)
            __hip_atomic_store(&tflags[b], TMAGIC,
                               __ATOMIC_RELAXED, __HIP_MEMORY_SCOPE_AGENT);
    }

    // ================= Phase 2: wait for this row-group's 16 tiles ===========
    // Block b consumes S rows 2b, 2b+1, which lie in tile-row b>>4 -- produced
    // by blocks (b>>4)*16 .. +15 (b's own group). 16 relaxed polls, no storm.
    {
        const int grp16 = (b >> 4) * 16;
        if (t < 16) {
            while (__hip_atomic_load(&tflags[grp16 + t], __ATOMIC_RELAXED,
                                     __HIP_MEMORY_SCOPE_AGENT) != TMAGIC)
                __builtin_amdgcn_s_sleep(8);
        }
        __syncthreads();
    }

    // ================= Phase 3: rows (verbatim body; srow via atomic loads) ==
    const int i0a = 2 * b;
    const int wave = t >> 6, lane = t & 63;
    const float C1   = 100.0f * 1.44269504088896340736f;
    const float CLIP = 50.0f  * 1.44269504088896340736f;

    for (int a = 0; a < 2; ++a) {
        const int i = i0a + a;
        __syncthreads();                   // protect reused buffers across a
        if (t == 0) npos_cnt = 0;
        if (t < 4) wave_part[t] = 0.f;
        __syncthreads();
        const int li = labels[i];
        for (int k = t; k < NN; k += 256) {
            srow[k] = __uint_as_float(
                __hip_atomic_load(&S_bits[i * NN + k], __ATOMIC_RELAXED,
                                  __HIP_MEMORY_SCOPE_AGENT));
            bool p  = (labels[k] == li) && (k != i);
            posf[k] = p ? 1.f : 0.f;
            if (p) { int idx = atomicAdd(&npos_cnt, 1); poslist[idx] = k; }
        }
        __syncthreads();

        const int cnt = npos_cnt;          // positives excluding self
        if (cnt == 0) {                    // n_pos == 1 -> per_anchor = 0
            if (t == 0) pa_out[a] = 0.f;
            continue;
        }

        float acc = 0.f;                   // lane-0 accumulation per wave
        for (int idx = wave; idx <= cnt; idx += 4) {   // idx==cnt -> j==i (eye)
            const int   j   = (idx == cnt) ? i : poslist[idx];
            const float sij = srow[j];
            float sum_all = 0.f, sum_pos = 0.f;
#pragma unroll
            for (int kk = 0; kk < 8; kk++) {
                const int k = lane + (kk << 6);
                float y = (sij - srow[k]) * C1;
                y = fminf(fmaxf(y, -CLIP), CLIP);
                float tt = 1.0f / (1.0f + exp2f(y));
                if (k == j) tt = 0.f;      // (1-eye)[j,k] factor
                sum_all += tt;
                sum_pos += tt * posf[k];   // posf[i]==0 excludes k==i
            }
#pragma unroll
            for (int off = 32; off; off >>= 1) {
                sum_all += __shfl_down(sum_all, off);
                sum_pos += __shfl_down(sum_pos, off);
            }
            if (lane == 0) {
                const float den = 1.0f + sum_all;
                acc += ((j == i) ? 1.0f : (1.0f + sum_pos)) / den;
            }
        }
        if (lane == 0) wave_part[wave] = acc;
        __syncthreads();
        if (t == 0) {
            pa_out[a] = (wave_part[0] + wave_part[1] + wave_part[2] + wave_part[3])
                      / (float)(cnt + 1);
        }
    }
    __syncthreads();

    // ================= Phase 4: r4-proven relaxed-atomic tail ================
    if (t == 0) {
        __hip_atomic_store(&pa_bits[i0a],     __float_as_uint(pa_out[0]),
                           __ATOMIC_RELAXED, __HIP_MEMORY_SCOPE_AGENT);
        __hip_atomic_store(&pa_bits[i0a + 1], __float_as_uint(pa_out[1]),
                           __ATOMIC_RELAXED, __HIP_MEMORY_SCOPE_AGENT);
        asm volatile("s_waitcnt vmcnt(0)" ::: "memory");
        __hip_atomic_store(&pflags[b], FMAGIC,
                           __ATOMIC_RELAXED, __HIP_MEMORY_SCOPE_AGENT);
    }

    if (b != 0) return;                    // finisher is block 0

    // block 0: wait for all pa flags; pa-flag from every block implies all
    // consumption finished grid-wide -> safe to clear tile flags too (replay).
    while (__hip_atomic_load(&pflags[t], __ATOMIC_RELAXED,
                             __HIP_MEMORY_SCOPE_AGENT) != FMAGIC)
        __builtin_amdgcn_s_sleep(8);
    __hip_atomic_store(&pflags[t], 0u, __ATOMIC_RELAXED, __HIP_MEMORY_SCOPE_AGENT);
    __hip_atomic_store(&tflags[t], 0u, __ATOMIC_RELAXED, __HIP_MEMORY_SCOPE_AGENT);
    __syncthreads();

    // final reduce (bitwise-identical round-0 tree)
    {
        float v0 = __uint_as_float(__hip_atomic_load(&pa_bits[t], __ATOMIC_RELAXED,
                                                     __HIP_MEMORY_SCOPE_AGENT));
        float v1 = __uint_as_float(__hip_atomic_load(&pa_bits[t + 256], __ATOMIC_RELAXED,
                                                     __HIP_MEMORY_SCOPE_AGENT));
        sh[t] = v0 + v1;
    }
    __syncthreads();
    for (int s = 128; s; s >>= 1) {
        if (t < s) sh[t] += sh[t + s];
        __syncthreads();
    }
    if (t == 0) out[0] = 1.0f - sh[0] / (float)NN;
}

extern "C" void kernel_launch(void* const* d_in, const int* in_sizes, int n_in,
                              void* d_out, int out_size, void* d_ws, size_t ws_size,
                              hipStream_t stream) {
    const float* preds  = (const float*)d_in[0];
    const int*   labels = (const int*)d_in[1];
    float* out = (float*)d_out;

    unsigned* S_bits  = (unsigned*)d_ws;           // 512*512 u32 = 1 MB
    unsigned* tflags  = S_bits + NN * NN;          // 256 u32
    unsigned* pa_bits = tflags + 256;              // 512 u32
    unsigned* pflags  = pa_bits + NN;              // 256 u32

    sap_one<<<256, 256, 0, stream>>>(preds, labels, S_bits, tflags,
                                     pa_bits, pflags, out);
}

// Round 10
// 73.803 us; speedup vs baseline: 1.1204x; 1.1204x over previous
//
#include <hip/hip_runtime.h>

#define NN 512
#define NB 256                 // 256 blocks x 2 anchors each
#define FMAGIC 0x5AD0F1A6u

// ---------------- single kernel: per-block srow dots + rows + atomic tail ----
// 256 blocks x 512 threads, 2 anchors per block (i = 2b, 2b+1).
// KEY FIX (r9 post-mortem): r2/r4 kept anchor fragments in "register arrays"
// but VGPR_Count=56 < the 64 regs they need -> compiler rematerialized them
// from GLOBAL P every batch => dot phase streamed ~3 MB/CU instead of 1 MB.
// Anchor rows now live in LDS (arow), so remat/hoist are both cheap; global
// traffic is the compulsory 1 MB/CU of B-rows only. Per-(i,k) dot order, lane
// slots (g+16c), and the 1/2/4/8 xor tree are unchanged -> srow bitwise-same.
// Rows phase: anchors 0/1 run CONCURRENTLY on waves 0-3 / 4-7, each using the
// r0-verified 4-wave stride-4 loop bitwise. Tail: r4-proven relaxed atomics.
__global__ __launch_bounds__(512) void sap_fused(const float* __restrict__ P,
                                                 const int* __restrict__ labels,
                                                 unsigned* __restrict__ pa_bits,
                                                 unsigned* __restrict__ flags,
                                                 float* __restrict__ out) {
    __shared__ float arow[2][NN];
    __shared__ float srow[2][NN];
    __shared__ int   labels_sh[NN];
    __shared__ float posf2[2][NN];
    __shared__ int   poslist2[2][NN];
    __shared__ int   npos2[2];
    __shared__ float wave_part2[2][4];
    __shared__ float pa_out[2];
    __shared__ float sh[256];

    const int t    = threadIdx.x;          // 0..511
    const int lane = t & 63;
    const int wave = t >> 6;               // 0..7
    const int g    = lane & 15;            // lane within 16-group
    const int grp  = lane >> 4;            // 0..3: row-group within wave
    const int b    = blockIdx.x;
    const int i0   = b * 2;

    // ---- stage labels + both anchor rows into LDS (coalesced)
    if (t < 128) ((int4*)labels_sh)[t] = ((const int4*)labels)[t];
    if (t < 256) ((float4*)&arow[0][0])[t] = ((const float4*)&P[i0 * NN])[t];
    __syncthreads();

    // ---- dot phase: wave w owns rows [64w, 64w+64); anchors read from LDS
    {
        const float4* A0 = (const float4*)&arow[0][0];
        const float4* A1 = (const float4*)&arow[1][0];
#pragma unroll 2
        for (int bb_ = 0; bb_ < 16; ++bb_) {
            const int k = wave * 64 + bb_ * 4 + grp;
            const float4* B = (const float4*)&P[k * NN];
            float s0 = 0.f, s1 = 0.f;
#pragma unroll
            for (int c = 0; c < 8; ++c) {
                const float4 bb = B[g + 16 * c];
                const float4 a0 = A0[g + 16 * c];   // LDS (broadcast x4 lanes)
                const float4 a1 = A1[g + 16 * c];   // LDS
                s0 += a0.x * bb.x; s0 += a0.y * bb.y;
                s0 += a0.z * bb.z; s0 += a0.w * bb.w;
                s1 += a1.x * bb.x; s1 += a1.y * bb.y;
                s1 += a1.z * bb.z; s1 += a1.w * bb.w;
            }
#pragma unroll
            for (int off = 1; off < 16; off <<= 1) {   // within the 16-group
                s0 += __shfl_xor(s0, off);
                s1 += __shfl_xor(s1, off);
            }
            if (g == 0) { srow[0][k] = s0; srow[1][k] = s1; }
        }
    }

    // ---- rows phase: both anchors concurrently (waves 0-3: a=0, 4-7: a=1)
    const float C1   = 100.0f * 1.44269504088896340736f;
    const float CLIP = 50.0f  * 1.44269504088896340736f;
    const int a  = wave >> 2;              // which anchor this wave serves
    const int w4 = wave & 3;               // wave index within the anchor's 4

    __syncthreads();                       // srow ready
    if (t == 0) { npos2[0] = 0; npos2[1] = 0; }
    if (t < 8) wave_part2[t >> 2][t & 3] = 0.f;
    __syncthreads();
    // build posf/poslist for both anchors (t == k, 0..511)
#pragma unroll
    for (int aa = 0; aa < 2; ++aa) {
        const int i  = i0 + aa;
        const int li = labels_sh[i];
        bool p = (labels_sh[t] == li) && (t != i);
        posf2[aa][t] = p ? 1.f : 0.f;
        if (p) { int idx = atomicAdd(&npos2[aa], 1); poslist2[aa][idx] = t; }
    }
    __syncthreads();

    {
        const int   i   = i0 + a;
        const int   cnt = npos2[a];        // positives excluding self
        float acc = 0.f;                   // lane-0 accumulation per wave
        if (cnt > 0) {
            const float* sr = srow[a];
            const float* pf = posf2[a];
            const int*   pl = poslist2[a];
            for (int idx = w4; idx <= cnt; idx += 4) {  // idx==cnt -> j==i (eye)
                const int   j   = (idx == cnt) ? i : pl[idx];
                const float sij = sr[j];
                float sum_all = 0.f, sum_pos = 0.f;
#pragma unroll
                for (int kk = 0; kk < 8; kk++) {
                    const int k = lane + (kk << 6);
                    float y = (sij - sr[k]) * C1;
                    y = fminf(fmaxf(y, -CLIP), CLIP);
                    float tt = 1.0f / (1.0f + exp2f(y));
                    if (k == j) tt = 0.f;      // (1-eye)[j,k] factor
                    sum_all += tt;
                    sum_pos += tt * pf[k];     // pf[i]==0 excludes k==i
                }
#pragma unroll
                for (int off = 32; off; off >>= 1) {
                    sum_all += __shfl_down(sum_all, off);
                    sum_pos += __shfl_down(sum_pos, off);
                }
                if (lane == 0) {
                    const float den = 1.0f + sum_all;
                    acc += ((j == i) ? 1.0f : (1.0f + sum_pos)) / den;
                }
            }
        }
        if (lane == 0) wave_part2[a][w4] = acc;
    }
    __syncthreads();
    if (t == 0) {
#pragma unroll
        for (int aa = 0; aa < 2; ++aa) {
            const int cnt2 = npos2[aa];
            if (cnt2 == 0) { pa_out[aa] = 0.f; continue; }
            float tot = wave_part2[aa][0] + wave_part2[aa][1]
                      + wave_part2[aa][2] + wave_part2[aa][3];
            pa_out[aa] = tot / (float)(cnt2 + 1);
        }
    }
    __syncthreads();

    // ---- publish this block's two per_anchor values + flag (relaxed atomics)
    if (t == 0) {
        __hip_atomic_store(&pa_bits[i0],     __float_as_uint(pa_out[0]),
                           __ATOMIC_RELAXED, __HIP_MEMORY_SCOPE_AGENT);
        __hip_atomic_store(&pa_bits[i0 + 1], __float_as_uint(pa_out[1]),
                           __ATOMIC_RELAXED, __HIP_MEMORY_SCOPE_AGENT);
        // order data-atomics before flag-atomic without any cache writeback:
        asm volatile("s_waitcnt vmcnt(0)" ::: "memory");
        __hip_atomic_store(&flags[b], FMAGIC,
                           __ATOMIC_RELAXED, __HIP_MEMORY_SCOPE_AGENT);
    }

    if (b != 0) return;                    // finisher is block 0

    // ---- block 0: wait for all flags (relaxed polls -> no L2 inv storm)
    if (t < NB) {
        while (__hip_atomic_load(&flags[t], __ATOMIC_RELAXED,
                                 __HIP_MEMORY_SCOPE_AGENT) != FMAGIC)
            __builtin_amdgcn_s_sleep(8);
        // reset for replay-robustness (0 != FMAGIC)
        __hip_atomic_store(&flags[t], 0u, __ATOMIC_RELAXED,
                           __HIP_MEMORY_SCOPE_AGENT);
    }
    __syncthreads();

    // ---- final reduce (bitwise-identical round-0 tree)
    if (t < 256) {
        float v0 = __uint_as_float(__hip_atomic_load(&pa_bits[t], __ATOMIC_RELAXED,
                                                     __HIP_MEMORY_SCOPE_AGENT));
        float v1 = __uint_as_float(__hip_atomic_load(&pa_bits[t + 256], __ATOMIC_RELAXED,
                                                     __HIP_MEMORY_SCOPE_AGENT));
        sh[t] = v0 + v1;
    }
    __syncthreads();
    for (int s = 128; s; s >>= 1) {
        if (t < s) sh[t] += sh[t + s];
        __syncthreads();
    }
    if (t == 0) out[0] = 1.0f - sh[0] / (float)NN;
}

extern "C" void kernel_launch(void* const* d_in, const int* in_sizes, int n_in,
                              void* d_out, int out_size, void* d_ws, size_t ws_size,
                              hipStream_t stream) {
    const float* preds  = (const float*)d_in[0];
    const int*   labels = (const int*)d_in[1];
    float* out = (float*)d_out;

    unsigned* pa_bits = (unsigned*)d_ws;           // 512 u32 (float bits)
    unsigned* flags   = pa_bits + NN;              // 256 u32

    sap_fused<<<NB, 512, 0, stream>>>(preds, labels, pa_bits, flags, out);
}